// Round 1
// baseline (1303.091 us; speedup 1.0000x reference)
//
#include <hip/hip_runtime.h>
#include <stdint.h>

#define HW 262144      // 512*512
#define LDIM 512

typedef __bf16 bf16x8 __attribute__((ext_vector_type(8)));
typedef float f32x4 __attribute__((ext_vector_type(4)));
typedef short s16x8 __attribute__((ext_vector_type(8)));
typedef short s16x4 __attribute__((ext_vector_type(4)));

__device__ __forceinline__ unsigned short f2bf(float f) {
  union { float f; unsigned u; } v; v.f = f;
  unsigned r = v.u + 0x7fffu + ((v.u >> 16) & 1u);
  return (unsigned short)(r >> 16);
}

__device__ __forceinline__ s16x8 pack_bf8(float4 a, float4 b) {
  s16x8 r;
  r[0] = (short)f2bf(a.x); r[1] = (short)f2bf(a.y);
  r[2] = (short)f2bf(a.z); r[3] = (short)f2bf(a.w);
  r[4] = (short)f2bf(b.x); r[5] = (short)f2bf(b.y);
  r[6] = (short)f2bf(b.z); r[7] = (short)f2bf(b.w);
  return r;
}

__device__ __forceinline__ f32x4 mfma16(bf16x8 a, bf16x8 b, f32x4 c) {
  return __builtin_amdgcn_mfma_f32_16x16x32_bf16(a, b, c, 0, 0, 0);
}

// ---------------------------------------------------------------------------
// Staging into LDS tile [128 rows (m/n)] x [32 k], row stride 40 (16B-aligned,
// ~2-way max conflict on b128 frag reads).
// MODE 0: source K-contiguous, bf16.  MODE 1: source K-contiguous, fp32 (cast).
// MODE 2: source M-contiguous (k strided), bf16 (transpose in regs).
// MODE 3: source M-contiguous, fp32 (transpose + cast).
// ---------------------------------------------------------------------------
template<int MODE>
__device__ __forceinline__ void stage_tile(short* __restrict__ dst,
                                           const void* __restrict__ base,
                                           size_t eoff, int ld, int kk, int mn0,
                                           int tid) {
  if constexpr (MODE == 0) {
    int r = tid >> 1, off = (tid & 1) * 16;
    const short* s = (const short*)base + eoff + (size_t)(mn0 + r) * ld + kk + off;
    s16x8 v0 = *(const s16x8*)s;
    s16x8 v1 = *(const s16x8*)(s + 8);
    *(s16x8*)(dst + r * 40 + off) = v0;
    *(s16x8*)(dst + r * 40 + off + 8) = v1;
  } else if constexpr (MODE == 1) {
    int r = tid >> 1, off = (tid & 1) * 16;
    const float* s = (const float*)base + eoff + (size_t)(mn0 + r) * ld + kk + off;
    float4 f0 = *(const float4*)s;
    float4 f1 = *(const float4*)(s + 4);
    float4 f2 = *(const float4*)(s + 8);
    float4 f3 = *(const float4*)(s + 12);
    *(s16x8*)(dst + r * 40 + off) = pack_bf8(f0, f1);
    *(s16x8*)(dst + r * 40 + off + 8) = pack_bf8(f2, f3);
  } else if constexpr (MODE == 2) {
    int mp = (tid & 63) * 2, k0 = (tid >> 6) * 8;
    const short* s = (const short*)base + eoff + (size_t)(kk + k0) * ld + mn0 + mp;
    s16x8 c0, c1;
#pragma unroll
    for (int j = 0; j < 8; ++j) {
      unsigned v = *(const unsigned*)(s + (size_t)j * ld);
      c0[j] = (short)(v & 0xffffu);
      c1[j] = (short)(v >> 16);
    }
    *(s16x8*)(dst + mp * 40 + k0) = c0;
    *(s16x8*)(dst + (mp + 1) * 40 + k0) = c1;
  } else {
    int mp = (tid & 63) * 2, k0 = (tid >> 6) * 8;
    const float* s = (const float*)base + eoff + (size_t)(kk + k0) * ld + mn0 + mp;
    s16x8 c0, c1;
#pragma unroll
    for (int j = 0; j < 8; ++j) {
      float2 v = *(const float2*)(s + (size_t)j * ld);
      c0[j] = (short)f2bf(v.x);
      c1[j] = (short)f2bf(v.y);
    }
    *(s16x8*)(dst + mp * 40 + k0) = c0;
    *(s16x8*)(dst + (mp + 1) * 40 + k0) = c1;
  }
}

// ---------------------------------------------------------------------------
// Generic 512x512 (per z) GEMM, C[m][n] = sum_k Als[m][k]*Bls[n][k].
// K = CH*512 via CH chunks (chunk element stride ac/bc). 128x128 block tile,
// BK=32, 4 waves as 2x2 of 64x64, 16x16x32 bf16 MFMA.
// ---------------------------------------------------------------------------
template<int AM, int BM, bool OBF, int CH>
__global__ __launch_bounds__(256, 2) void gemm_k(
    const void* __restrict__ A0, long az, int zshA, long ac, int lda,
    const void* __restrict__ B0, long bz, int zshB, long bc, int ldb,
    void* __restrict__ C0, long cz) {
  __shared__ __align__(16) short As[128 * 40];
  __shared__ __align__(16) short Bs[128 * 40];
  int tid = threadIdx.x;
  int z = blockIdx.z;
  int m0g = blockIdx.y * 128, n0g = blockIdx.x * 128;
  size_t aoffz = (size_t)(z >> zshA) * (size_t)az;
  size_t boffz = (size_t)(z >> zshB) * (size_t)bz;
  int lane = tid & 63, wv = tid >> 6;
  int wm = (wv >> 1) * 64, wn = (wv & 1) * 64;
  int fr = lane & 15, q = lane >> 4;

  f32x4 acc[4][4];
#pragma unroll
  for (int mi = 0; mi < 4; ++mi)
#pragma unroll
    for (int ni = 0; ni < 4; ++ni) acc[mi][ni] = (f32x4){0.f, 0.f, 0.f, 0.f};

  for (int kidx = 0; kidx < CH * 16; ++kidx) {
    int chunk = kidx >> 4;
    int kk = (kidx & 15) * 32;
    stage_tile<AM>(As, A0, aoffz + (size_t)chunk * (size_t)ac, lda, kk, m0g, tid);
    stage_tile<BM>(Bs, B0, boffz + (size_t)chunk * (size_t)bc, ldb, kk, n0g, tid);
    __syncthreads();
    bf16x8 af[4], bg[4];
#pragma unroll
    for (int mi = 0; mi < 4; ++mi)
      af[mi] = *(const bf16x8*)(As + (wm + mi * 16 + fr) * 40 + q * 8);
#pragma unroll
    for (int ni = 0; ni < 4; ++ni)
      bg[ni] = *(const bf16x8*)(Bs + (wn + ni * 16 + fr) * 40 + q * 8);
#pragma unroll
    for (int mi = 0; mi < 4; ++mi)
#pragma unroll
      for (int ni = 0; ni < 4; ++ni)
        acc[mi][ni] = mfma16(af[mi], bg[ni], acc[mi][ni]);
    __syncthreads();
  }

  size_t coff = (size_t)z * (size_t)cz;
#pragma unroll
  for (int mi = 0; mi < 4; ++mi)
#pragma unroll
    for (int ni = 0; ni < 4; ++ni) {
      int row = m0g + wm + mi * 16 + q * 4;
      int col = n0g + wn + ni * 16 + fr;
#pragma unroll
      for (int r = 0; r < 4; ++r) {
        float v = acc[mi][ni][r];
        if constexpr (OBF) {
          ((short*)C0)[coff + (size_t)(row + r) * LDIM + col] = (short)f2bf(v);
        } else {
          ((float*)C0)[coff + (size_t)(row + r) * LDIM + col] = v;
        }
      }
    }
}

// ---------------------------------------------------------------------------
// Q/K conv: for 128 spatial positions, compute 32 output channels
// (tq 0-7, tk 8-15, fq 16-23, fk 24-31) = W[32x64] @ x[64 x 128] via MFMA.
// ---------------------------------------------------------------------------
__global__ __launch_bounds__(256, 2) void conv_qk_k(
    const float* __restrict__ xn,
    const float* __restrict__ tqw, const float* __restrict__ tqb,
    const float* __restrict__ tkw, const float* __restrict__ tkb,
    const float* __restrict__ fqw, const float* __restrict__ fqb,
    const float* __restrict__ fkw, const float* __restrict__ fkb,
    short* __restrict__ QT, short* __restrict__ KT,
    short* __restrict__ QF, short* __restrict__ KF) {
  __shared__ __align__(16) short As[128 * 72];   // x^T tile [p][ci]
  __shared__ __align__(16) short Ws[32 * 72];    // weights [co][ci]
  __shared__ float bia[32];
  int tid = threadIdx.x;
  int n = blockIdx.x >> 11;
  int p0 = (blockIdx.x & 2047) << 7;
  {
    int co = tid >> 3, k0 = (tid & 7) * 8;
    const float* wsrc = (co < 8) ? tqw : (co < 16) ? tkw : (co < 24) ? fqw : fkw;
    const float* sp = wsrc + (co & 7) * 64 + k0;
    float4 f0 = *(const float4*)sp;
    float4 f1 = *(const float4*)(sp + 4);
    *(s16x8*)(Ws + co * 72 + k0) = pack_bf8(f0, f1);
    if (tid < 32) {
      const float* bsrc = (tid < 8) ? tqb : (tid < 16) ? tkb : (tid < 24) ? fqb : fkb;
      bia[tid] = bsrc[tid & 7];
    }
  }
  {
    int mp = (tid & 31) * 4, k0 = (tid >> 5) * 8;
    const float* sp = xn + ((size_t)(n * 64 + k0)) * HW + p0 + mp;
    s16x8 t0, t1, t2, t3;
#pragma unroll
    for (int j = 0; j < 8; ++j) {
      float4 vv = *(const float4*)(sp + (size_t)j * HW);
      t0[j] = (short)f2bf(vv.x);
      t1[j] = (short)f2bf(vv.y);
      t2[j] = (short)f2bf(vv.z);
      t3[j] = (short)f2bf(vv.w);
    }
    *(s16x8*)(As + (mp + 0) * 72 + k0) = t0;
    *(s16x8*)(As + (mp + 1) * 72 + k0) = t1;
    *(s16x8*)(As + (mp + 2) * 72 + k0) = t2;
    *(s16x8*)(As + (mp + 3) * 72 + k0) = t3;
  }
  __syncthreads();
  int lane = tid & 63, wv = tid >> 6, fr = lane & 15, q = lane >> 4;
  int wm = wv * 32;
  f32x4 acc[2][2];
#pragma unroll
  for (int mi = 0; mi < 2; ++mi)
#pragma unroll
    for (int ni = 0; ni < 2; ++ni) acc[mi][ni] = (f32x4){0.f, 0.f, 0.f, 0.f};
#pragma unroll
  for (int ks = 0; ks < 2; ++ks) {
    bf16x8 af[2], bf_[2];
#pragma unroll
    for (int mi = 0; mi < 2; ++mi)
      af[mi] = *(const bf16x8*)(As + (wm + mi * 16 + fr) * 72 + ks * 32 + q * 8);
#pragma unroll
    for (int ni = 0; ni < 2; ++ni)
      bf_[ni] = *(const bf16x8*)(Ws + (ni * 16 + fr) * 72 + ks * 32 + q * 8);
#pragma unroll
    for (int mi = 0; mi < 2; ++mi)
#pragma unroll
      for (int ni = 0; ni < 2; ++ni)
        acc[mi][ni] = mfma16(af[mi], bf_[ni], acc[mi][ni]);
  }
#pragma unroll
  for (int mi = 0; mi < 2; ++mi)
#pragma unroll
    for (int ni = 0; ni < 2; ++ni) {
      int pl = wm + mi * 16 + q * 4;
      int co = ni * 16 + fr;
      float b = bia[co];
      short* dstt = (co < 8) ? QT : (co < 16) ? KT : (co < 24) ? QF : KF;
      short* d = dstt + ((size_t)(n * 8 + (co & 7))) * HW + p0 + pl;
      s16x4 sv;
#pragma unroll
      for (int r = 0; r < 4; ++r) sv[r] = (short)f2bf(acc[mi][ni][r] + b);
      *(s16x4*)d = sv;
    }
}

// ---------------------------------------------------------------------------
// Row softmax over 512 logits; fp32 in -> bf16 out. One wave per row.
// ---------------------------------------------------------------------------
__global__ __launch_bounds__(256, 4) void softmax_k(const float* __restrict__ E,
                                                    short* __restrict__ A) {
  int tid = threadIdx.x;
  int lane = tid & 63, wv = tid >> 6;
  size_t row = (size_t)blockIdx.x * 4 + wv;
  const float* e = E + row * LDIM + lane * 8;
  float4 a = *(const float4*)e;
  float4 b = *(const float4*)(e + 4);
  float v[8] = {a.x, a.y, a.z, a.w, b.x, b.y, b.z, b.w};
  float m = v[0];
#pragma unroll
  for (int j = 1; j < 8; ++j) m = fmaxf(m, v[j]);
#pragma unroll
  for (int off = 32; off >= 1; off >>= 1) m = fmaxf(m, __shfl_xor(m, off));
  float s = 0.f;
#pragma unroll
  for (int j = 0; j < 8; ++j) {
    v[j] = __expf(v[j] - m);
    s += v[j];
  }
#pragma unroll
  for (int off = 32; off >= 1; off >>= 1) s += __shfl_xor(s, off);
  float inv = 1.f / s;
  s16x8 o;
#pragma unroll
  for (int j = 0; j < 8; ++j) o[j] = (short)f2bf(v[j] * inv);
  *(s16x8*)(A + row * LDIM + lane * 8) = o;
}

// ---------------------------------------------------------------------------
// Final: out = 3x + gt*(Wt@Zt + bt) + gf*(Wf@Zf + bf), per 128-position tile,
// both 64x64 convs via MFMA, fused with elementwise epilogue.
// ---------------------------------------------------------------------------
__global__ __launch_bounds__(256, 2) void final_k(
    const short* __restrict__ ZT, const short* __restrict__ ZF,
    const float* __restrict__ xn,
    const float* __restrict__ tvw, const float* __restrict__ tvb,
    const float* __restrict__ fvw, const float* __restrict__ fvb,
    const float* __restrict__ tg, const float* __restrict__ fg,
    float* __restrict__ outn) {
  __shared__ __align__(16) short Zts[128 * 72];
  __shared__ __align__(16) short Zfs[128 * 72];
  __shared__ __align__(16) short Wv[128 * 72];  // [0:64)=tv_w, [64:128)=fv_w
  __shared__ float bia[128];
  int tid = threadIdx.x;
  int n = blockIdx.x >> 11;
  int p0 = (blockIdx.x & 2047) << 7;
  {
    int co = tid >> 1, k0 = (tid & 1) * 32;
    const float* wsrc = (co < 64) ? (tvw + co * 64) : (fvw + (co - 64) * 64);
#pragma unroll
    for (int g = 0; g < 4; ++g) {
      float4 f0 = *(const float4*)(wsrc + k0 + g * 8);
      float4 f1 = *(const float4*)(wsrc + k0 + g * 8 + 4);
      *(s16x8*)(Wv + co * 72 + k0 + g * 8) = pack_bf8(f0, f1);
    }
    if (tid < 128) bia[tid] = (tid < 64) ? tvb[tid] : fvb[tid - 64];
  }
  {
    int mp = (tid & 31) * 4, k0 = (tid >> 5) * 8;
    const short* spT = ZT + ((size_t)(n * 64 + k0)) * HW + p0 + mp;
    const short* spF = ZF + ((size_t)(n * 64 + k0)) * HW + p0 + mp;
    s16x8 t0, t1, t2, t3;
#pragma unroll
    for (int j = 0; j < 8; ++j) {
      s16x4 vv = *(const s16x4*)(spT + (size_t)j * HW);
      t0[j] = vv[0]; t1[j] = vv[1]; t2[j] = vv[2]; t3[j] = vv[3];
    }
    *(s16x8*)(Zts + (mp + 0) * 72 + k0) = t0;
    *(s16x8*)(Zts + (mp + 1) * 72 + k0) = t1;
    *(s16x8*)(Zts + (mp + 2) * 72 + k0) = t2;
    *(s16x8*)(Zts + (mp + 3) * 72 + k0) = t3;
#pragma unroll
    for (int j = 0; j < 8; ++j) {
      s16x4 vv = *(const s16x4*)(spF + (size_t)j * HW);
      t0[j] = vv[0]; t1[j] = vv[1]; t2[j] = vv[2]; t3[j] = vv[3];
    }
    *(s16x8*)(Zfs + (mp + 0) * 72 + k0) = t0;
    *(s16x8*)(Zfs + (mp + 1) * 72 + k0) = t1;
    *(s16x8*)(Zfs + (mp + 2) * 72 + k0) = t2;
    *(s16x8*)(Zfs + (mp + 3) * 72 + k0) = t3;
  }
  __syncthreads();
  int lane = tid & 63, wv = tid >> 6, fr = lane & 15, q = lane >> 4;
  int wm = wv * 32;
  f32x4 at_[2][4], af_[2][4];
#pragma unroll
  for (int mi = 0; mi < 2; ++mi)
#pragma unroll
    for (int ni = 0; ni < 4; ++ni) {
      at_[mi][ni] = (f32x4){0.f, 0.f, 0.f, 0.f};
      af_[mi][ni] = (f32x4){0.f, 0.f, 0.f, 0.f};
    }
#pragma unroll
  for (int ks = 0; ks < 2; ++ks) {
    bf16x8 zt_[2], zf_[2], wt_[4], wf_[4];
#pragma unroll
    for (int mi = 0; mi < 2; ++mi) {
      zt_[mi] = *(const bf16x8*)(Zts + (wm + mi * 16 + fr) * 72 + ks * 32 + q * 8);
      zf_[mi] = *(const bf16x8*)(Zfs + (wm + mi * 16 + fr) * 72 + ks * 32 + q * 8);
    }
#pragma unroll
    for (int ni = 0; ni < 4; ++ni) {
      wt_[ni] = *(const bf16x8*)(Wv + (ni * 16 + fr) * 72 + ks * 32 + q * 8);
      wf_[ni] = *(const bf16x8*)(Wv + (64 + ni * 16 + fr) * 72 + ks * 32 + q * 8);
    }
#pragma unroll
    for (int mi = 0; mi < 2; ++mi)
#pragma unroll
      for (int ni = 0; ni < 4; ++ni) {
        at_[mi][ni] = mfma16(zt_[mi], wt_[ni], at_[mi][ni]);
        af_[mi][ni] = mfma16(zf_[mi], wf_[ni], af_[mi][ni]);
      }
  }
  float gtv = tg[0], gfv = fg[0];
#pragma unroll
  for (int mi = 0; mi < 2; ++mi)
#pragma unroll
    for (int ni = 0; ni < 4; ++ni) {
      int pl = wm + mi * 16 + q * 4;
      int co = ni * 16 + fr;
      size_t idx = ((size_t)(n * 64 + co)) * HW + p0 + pl;
      float4 xv = *(const float4*)(xn + idx);
      float bt = bia[co], bff = bia[64 + co];
      float4 ov;
      ov.x = 3.f * xv.x + gtv * (at_[mi][ni][0] + bt) + gfv * (af_[mi][ni][0] + bff);
      ov.y = 3.f * xv.y + gtv * (at_[mi][ni][1] + bt) + gfv * (af_[mi][ni][1] + bff);
      ov.z = 3.f * xv.z + gtv * (at_[mi][ni][2] + bt) + gfv * (af_[mi][ni][2] + bff);
      ov.w = 3.f * xv.w + gtv * (at_[mi][ni][3] + bt) + gfv * (af_[mi][ni][3] + bff);
      *(float4*)(outn + idx) = ov;
    }
}

// ---------------------------------------------------------------------------
extern "C" void kernel_launch(void* const* d_in, const int* in_sizes, int n_in,
                              void* d_out, int out_size, void* d_ws, size_t ws_size,
                              hipStream_t stream) {
  (void)in_sizes; (void)n_in; (void)out_size;
  const float* x   = (const float*)d_in[0];
  const float* tqw = (const float*)d_in[1];
  const float* tqb = (const float*)d_in[2];
  const float* tkw = (const float*)d_in[3];
  const float* tkb = (const float*)d_in[4];
  const float* tvw = (const float*)d_in[5];
  const float* tvb = (const float*)d_in[6];
  const float* tg  = (const float*)d_in[7];
  const float* fqw = (const float*)d_in[8];
  const float* fqb = (const float*)d_in[9];
  const float* fkw = (const float*)d_in[10];
  const float* fkb = (const float*)d_in[11];
  const float* fvw = (const float*)d_in[12];
  const float* fvb = (const float*)d_in[13];
  const float* fg  = (const float*)d_in[14];
  float* out = (float*)d_out;

  const size_t per_n = 85458944;  // 4*8*HW*2*4 + 2*64*HW*2 + HW*4 + HW*2 (bytes)
  int nb = (ws_size >= 4 * per_n) ? 4 : (ws_size >= 2 * per_n) ? 2 : 1;

  char* w = (char*)d_ws;
  size_t sz_qk = (size_t)nb * 8 * HW * 2;        // one of QT/KT/QF/KF
  size_t sz_z  = (size_t)nb * 64 * HW * 2;       // one of ZT/ZF
  short* QT = (short*)(w);
  short* KT = (short*)(w + sz_qk);
  short* QF = (short*)(w + 2 * sz_qk);
  short* KF = (short*)(w + 3 * sz_qk);
  short* ZT = (short*)(w + 4 * sz_qk);
  short* ZF = (short*)(w + 4 * sz_qk + sz_z);
  float* Eb = (float*)(w + 4 * sz_qk + 2 * sz_z);
  short* Ab = (short*)(w + 4 * sz_qk + 2 * sz_z + (size_t)nb * HW * 4);

  for (int n0 = 0; n0 < 4; n0 += nb) {
    const float* xn = x + (size_t)n0 * 64 * HW;
    float* outn = out + (size_t)n0 * 64 * HW;
    conv_qk_k<<<dim3(nb * 2048), dim3(256), 0, stream>>>(
        xn, tqw, tqb, tkw, tkb, fqw, fqb, fkw, fkb, QT, KT, QF, KF);
    // energy_t = sum_c Qt[c] @ Kt[c]^T  -> E (fp32)
    gemm_k<0, 0, false, 8><<<dim3(4, 4, nb), dim3(256), 0, stream>>>(
        QT, 2097152L, 0, 262144L, 512, KT, 2097152L, 0, 262144L, 512, Eb, 262144L);
    softmax_k<<<dim3(nb * 128), dim3(256), 0, stream>>>(Eb, Ab);
    // Zt[n,c] = At[n] @ x[n,c]   (A: bf16 K-contig; B: x fp32, k-strided)
    gemm_k<0, 3, true, 1><<<dim3(4, 4, nb * 64), dim3(256), 0, stream>>>(
        Ab, 262144L, 6, 0L, 512, xn, 262144L, 0, 0L, 512, ZT, 262144L);
    // energy_f = sum_c Qf[c]^T @ Kf[c] -> E (fp32); both operands k-strided
    gemm_k<2, 2, false, 8><<<dim3(4, 4, nb), dim3(256), 0, stream>>>(
        QF, 2097152L, 0, 262144L, 512, KF, 2097152L, 0, 262144L, 512, Eb, 262144L);
    softmax_k<<<dim3(nb * 128), dim3(256), 0, stream>>>(Eb, Ab);
    // Zf[n,c] = x[n,c] @ Af[n]^T  (A: x fp32 K-contig; B: attn bf16 K-contig)
    gemm_k<1, 0, true, 1><<<dim3(4, 4, nb * 64), dim3(256), 0, stream>>>(
        xn, 262144L, 0, 0L, 512, Ab, 262144L, 6, 0L, 512, ZF, 262144L);
    final_k<<<dim3(nb * 2048), dim3(256), 0, stream>>>(
        ZT, ZF, xn, tvw, tvb, fvw, fvb, tg, fg, outn);
  }
}

// Round 2
// 1025.029 us; speedup vs baseline: 1.2713x; 1.2713x over previous
//
#include <hip/hip_runtime.h>
#include <stdint.h>

#define HW 262144      // 512*512
#define LDIM 512

typedef __bf16 bf16x8 __attribute__((ext_vector_type(8)));
typedef float f32x4 __attribute__((ext_vector_type(4)));
typedef short s16x8 __attribute__((ext_vector_type(8)));
typedef short s16x4 __attribute__((ext_vector_type(4)));

__device__ __forceinline__ unsigned short f2bf(float f) {
  union { float f; unsigned u; } v; v.f = f;
  unsigned r = v.u + 0x7fffu + ((v.u >> 16) & 1u);
  return (unsigned short)(r >> 16);
}

__device__ __forceinline__ s16x8 pack_bf8(float4 a, float4 b) {
  s16x8 r;
  r[0] = (short)f2bf(a.x); r[1] = (short)f2bf(a.y);
  r[2] = (short)f2bf(a.z); r[3] = (short)f2bf(a.w);
  r[4] = (short)f2bf(b.x); r[5] = (short)f2bf(b.y);
  r[6] = (short)f2bf(b.z); r[7] = (short)f2bf(b.w);
  return r;
}

__device__ __forceinline__ f32x4 mfma16(bf16x8 a, bf16x8 b, f32x4 c) {
  return __builtin_amdgcn_mfma_f32_16x16x32_bf16(a, b, c, 0, 0, 0);
}

// ---------------------------------------------------------------------------
// cast x (fp32) -> xb bf16 [c][h][w] and xt bf16 [c][w][h] (64x64 LDS transpose)
// grid: (8 wtile, 8 htile, nb*64)
// ---------------------------------------------------------------------------
__global__ __launch_bounds__(256) void cast_k(const float* __restrict__ x,
                                              short* __restrict__ xb,
                                              short* __restrict__ xt) {
  __shared__ short L[64][72];
  int z = blockIdx.z;
  int h0 = blockIdx.y * 64, w0 = blockIdx.x * 64;
  int tid = threadIdx.x;
  size_t base = (size_t)z * HW;
  int hl = tid >> 4;          // 0..15
  int wl = (tid & 15) * 4;    // 0..60
#pragma unroll
  for (int it = 0; it < 4; ++it) {
    int h = h0 + hl + it * 16;
    float4 v = *(const float4*)(x + base + (size_t)h * 512 + w0 + wl);
    s16x4 b;
    b[0] = (short)f2bf(v.x); b[1] = (short)f2bf(v.y);
    b[2] = (short)f2bf(v.z); b[3] = (short)f2bf(v.w);
    *(s16x4*)(xb + base + (size_t)h * 512 + w0 + wl) = b;
    L[wl + 0][hl + it * 16] = b[0];
    L[wl + 1][hl + it * 16] = b[1];
    L[wl + 2][hl + it * 16] = b[2];
    L[wl + 3][hl + it * 16] = b[3];
  }
  __syncthreads();
#pragma unroll
  for (int it = 0; it < 4; ++it) {
    int w = hl + it * 16;
    s16x4 v = *(const s16x4*)(&L[w][wl]);   // wl is h-offset here
    *(s16x4*)(xt + base + (size_t)(w0 + w) * 512 + h0 + wl) = v;
  }
}

// ---------------------------------------------------------------------------
// Staging into LDS tile [128 rows (m/n)] x [32 k], row stride 40.
// MODE 0: source K-contiguous bf16.  MODE 2: source M-contiguous bf16
// (k strided, transpose in regs).
// ---------------------------------------------------------------------------
template<int MODE>
__device__ __forceinline__ void stage_tile(short* __restrict__ dst,
                                           const void* __restrict__ base,
                                           size_t eoff, int ld, int kk, int mn0,
                                           int tid) {
  if constexpr (MODE == 0) {
    int r = tid >> 1, off = (tid & 1) * 16;
    const short* s = (const short*)base + eoff + (size_t)(mn0 + r) * ld + kk + off;
    s16x8 v0 = *(const s16x8*)s;
    s16x8 v1 = *(const s16x8*)(s + 8);
    *(s16x8*)(dst + r * 40 + off) = v0;
    *(s16x8*)(dst + r * 40 + off + 8) = v1;
  } else {
    int mp = (tid & 63) * 2, k0 = (tid >> 6) * 8;
    const short* s = (const short*)base + eoff + (size_t)(kk + k0) * ld + mn0 + mp;
    s16x8 c0, c1;
#pragma unroll
    for (int j = 0; j < 8; ++j) {
      unsigned v = *(const unsigned*)(s + (size_t)j * ld);
      c0[j] = (short)(v & 0xffffu);
      c1[j] = (short)(v >> 16);
    }
    *(s16x8*)(dst + mp * 40 + k0) = c0;
    *(s16x8*)(dst + (mp + 1) * 40 + k0) = c1;
  }
}

// ---------------------------------------------------------------------------
// Generic 512x512 (per z) GEMM, C[m][n] = sum_k Als[m][k]*Bls[n][k].
// K = 512 per block (CH always 1 now; split-K handled by caller via z).
// 128x128 block tile, BK=32, 4 waves as 2x2 of 64x64, 16x16x32 bf16 MFMA.
// ---------------------------------------------------------------------------
template<int AM, int BM, bool OBF>
__global__ __launch_bounds__(256, 2) void gemm_k(
    const void* __restrict__ A0, long az, int zshA, int lda,
    const void* __restrict__ B0, long bz, int zshB, int ldb,
    void* __restrict__ C0, long cz) {
  __shared__ __align__(16) short As[128 * 40];
  __shared__ __align__(16) short Bs[128 * 40];
  int tid = threadIdx.x;
  int z = blockIdx.z;
  int m0g = blockIdx.y * 128, n0g = blockIdx.x * 128;
  size_t aoffz = (size_t)(z >> zshA) * (size_t)az;
  size_t boffz = (size_t)(z >> zshB) * (size_t)bz;
  int lane = tid & 63, wv = tid >> 6;
  int wm = (wv >> 1) * 64, wn = (wv & 1) * 64;
  int fr = lane & 15, q = lane >> 4;

  f32x4 acc[4][4];
#pragma unroll
  for (int mi = 0; mi < 4; ++mi)
#pragma unroll
    for (int ni = 0; ni < 4; ++ni) acc[mi][ni] = (f32x4){0.f, 0.f, 0.f, 0.f};

  for (int kidx = 0; kidx < 16; ++kidx) {
    int kk = kidx * 32;
    stage_tile<AM>(As, A0, aoffz, lda, kk, m0g, tid);
    stage_tile<BM>(Bs, B0, boffz, ldb, kk, n0g, tid);
    __syncthreads();
    bf16x8 af[4], bg[4];
#pragma unroll
    for (int mi = 0; mi < 4; ++mi)
      af[mi] = *(const bf16x8*)(As + (wm + mi * 16 + fr) * 40 + q * 8);
#pragma unroll
    for (int ni = 0; ni < 4; ++ni)
      bg[ni] = *(const bf16x8*)(Bs + (wn + ni * 16 + fr) * 40 + q * 8);
#pragma unroll
    for (int mi = 0; mi < 4; ++mi)
#pragma unroll
      for (int ni = 0; ni < 4; ++ni)
        acc[mi][ni] = mfma16(af[mi], bg[ni], acc[mi][ni]);
    __syncthreads();
  }

  size_t coff = (size_t)z * (size_t)cz;
#pragma unroll
  for (int mi = 0; mi < 4; ++mi)
#pragma unroll
    for (int ni = 0; ni < 4; ++ni) {
      int row = m0g + wm + mi * 16 + q * 4;
      int col = n0g + wn + ni * 16 + fr;
#pragma unroll
      for (int r = 0; r < 4; ++r) {
        float v = acc[mi][ni][r];
        if constexpr (OBF) {
          ((short*)C0)[coff + (size_t)(row + r) * LDIM + col] = (short)f2bf(v);
        } else {
          ((float*)C0)[coff + (size_t)(row + r) * LDIM + col] = v;
        }
      }
    }
}

// ---------------------------------------------------------------------------
// Q/K conv from bf16 xb: 128 spatial positions x 32 output channels
// (tq 0-7, tk 8-15, fq 16-23, fk 24-31) = W[32x64] @ x[64 x 128] via MFMA.
// ---------------------------------------------------------------------------
__global__ __launch_bounds__(256, 2) void conv_qk_k(
    const short* __restrict__ xb,
    const float* __restrict__ tqw, const float* __restrict__ tqb,
    const float* __restrict__ tkw, const float* __restrict__ tkb,
    const float* __restrict__ fqw, const float* __restrict__ fqb,
    const float* __restrict__ fkw, const float* __restrict__ fkb,
    short* __restrict__ QT, short* __restrict__ KT,
    short* __restrict__ QF, short* __restrict__ KF) {
  __shared__ __align__(16) short As[128 * 72];   // x^T tile [p][ci]
  __shared__ __align__(16) short Ws[32 * 72];    // weights [co][ci]
  __shared__ float bia[32];
  int tid = threadIdx.x;
  int n = blockIdx.x >> 11;
  int p0 = (blockIdx.x & 2047) << 7;
  {
    int co = tid >> 3, k0 = (tid & 7) * 8;
    const float* wsrc = (co < 8) ? tqw : (co < 16) ? tkw : (co < 24) ? fqw : fkw;
    const float* sp = wsrc + (co & 7) * 64 + k0;
    float4 f0 = *(const float4*)sp;
    float4 f1 = *(const float4*)(sp + 4);
    *(s16x8*)(Ws + co * 72 + k0) = pack_bf8(f0, f1);
    if (tid < 32) {
      const float* bsrc = (tid < 8) ? tqb : (tid < 16) ? tkb : (tid < 24) ? fqb : fkb;
      bia[tid] = bsrc[tid & 7];
    }
  }
  {
    int mp = (tid & 31) * 4, k0 = (tid >> 5) * 8;
    const short* sp = xb + ((size_t)(n * 64 + k0)) * HW + p0 + mp;
    s16x8 t0, t1, t2, t3;
#pragma unroll
    for (int j = 0; j < 8; ++j) {
      s16x4 vv = *(const s16x4*)(sp + (size_t)j * HW);
      t0[j] = vv[0]; t1[j] = vv[1]; t2[j] = vv[2]; t3[j] = vv[3];
    }
    *(s16x8*)(As + (mp + 0) * 72 + k0) = t0;
    *(s16x8*)(As + (mp + 1) * 72 + k0) = t1;
    *(s16x8*)(As + (mp + 2) * 72 + k0) = t2;
    *(s16x8*)(As + (mp + 3) * 72 + k0) = t3;
  }
  __syncthreads();
  int lane = tid & 63, wv = tid >> 6, fr = lane & 15, q = lane >> 4;
  int wm = wv * 32;
  f32x4 acc[2][2];
#pragma unroll
  for (int mi = 0; mi < 2; ++mi)
#pragma unroll
    for (int ni = 0; ni < 2; ++ni) acc[mi][ni] = (f32x4){0.f, 0.f, 0.f, 0.f};
#pragma unroll
  for (int ks = 0; ks < 2; ++ks) {
    bf16x8 af[2], bf_[2];
#pragma unroll
    for (int mi = 0; mi < 2; ++mi)
      af[mi] = *(const bf16x8*)(As + (wm + mi * 16 + fr) * 72 + ks * 32 + q * 8);
#pragma unroll
    for (int ni = 0; ni < 2; ++ni)
      bf_[ni] = *(const bf16x8*)(Ws + (ni * 16 + fr) * 72 + ks * 32 + q * 8);
#pragma unroll
    for (int mi = 0; mi < 2; ++mi)
#pragma unroll
      for (int ni = 0; ni < 2; ++ni)
        acc[mi][ni] = mfma16(af[mi], bf_[ni], acc[mi][ni]);
  }
#pragma unroll
  for (int mi = 0; mi < 2; ++mi)
#pragma unroll
    for (int ni = 0; ni < 2; ++ni) {
      int pl = wm + mi * 16 + q * 4;
      int co = ni * 16 + fr;
      float b = bia[co];
      short* dstt = (co < 8) ? QT : (co < 16) ? KT : (co < 24) ? QF : KF;
      short* d = dstt + ((size_t)(n * 8 + (co & 7))) * HW + p0 + pl;
      s16x4 sv;
#pragma unroll
      for (int r = 0; r < 4; ++r) sv[r] = (short)f2bf(acc[mi][ni][r] + b);
      *(s16x4*)d = sv;
    }
}

// ---------------------------------------------------------------------------
// Row softmax over 512 logits with 8-way split-K partial sum.
// Partials: Ep[(n*8+cc)*HW + h*512 + g], fp32. One wave per row.
// ---------------------------------------------------------------------------
__global__ __launch_bounds__(256, 4) void softmax8_k(const float* __restrict__ Ep,
                                                     short* __restrict__ A) {
  int tid = threadIdx.x;
  int lane = tid & 63, wv = tid >> 6;
  int row = blockIdx.x * 4 + wv;        // n*512 + h
  int n = row >> 9, h = row & 511;
  const float* base = Ep + (size_t)(n * 8) * HW + (size_t)h * 512 + lane * 8;
  float v[8] = {0.f, 0.f, 0.f, 0.f, 0.f, 0.f, 0.f, 0.f};
#pragma unroll
  for (int cc = 0; cc < 8; ++cc) {
    const float* e = base + (size_t)cc * HW;
    float4 a = *(const float4*)e;
    float4 b = *(const float4*)(e + 4);
    v[0] += a.x; v[1] += a.y; v[2] += a.z; v[3] += a.w;
    v[4] += b.x; v[5] += b.y; v[6] += b.z; v[7] += b.w;
  }
  float m = v[0];
#pragma unroll
  for (int j = 1; j < 8; ++j) m = fmaxf(m, v[j]);
#pragma unroll
  for (int off = 32; off >= 1; off >>= 1) m = fmaxf(m, __shfl_xor(m, off));
  float s = 0.f;
#pragma unroll
  for (int j = 0; j < 8; ++j) {
    v[j] = __expf(v[j] - m);
    s += v[j];
  }
#pragma unroll
  for (int off = 32; off >= 1; off >>= 1) s += __shfl_xor(s, off);
  float inv = 1.f / s;
  s16x8 o;
#pragma unroll
  for (int j = 0; j < 8; ++j) o[j] = (short)f2bf(v[j] * inv);
  *(s16x8*)(A + (size_t)row * LDIM + lane * 8) = o;
}

// ---------------------------------------------------------------------------
// Final: out = 3x + gt*(Wt@Zt + bt) + gf*(Wf@Zf + bf), per 128-position tile.
// ---------------------------------------------------------------------------
__global__ __launch_bounds__(256, 2) void final_k(
    const short* __restrict__ ZT, const short* __restrict__ ZF,
    const float* __restrict__ xn,
    const float* __restrict__ tvw, const float* __restrict__ tvb,
    const float* __restrict__ fvw, const float* __restrict__ fvb,
    const float* __restrict__ tg, const float* __restrict__ fg,
    float* __restrict__ outn) {
  __shared__ __align__(16) short Zts[128 * 72];
  __shared__ __align__(16) short Zfs[128 * 72];
  __shared__ __align__(16) short Wv[128 * 72];  // [0:64)=tv_w, [64:128)=fv_w
  __shared__ float bia[128];
  int tid = threadIdx.x;
  int n = blockIdx.x >> 11;
  int p0 = (blockIdx.x & 2047) << 7;
  {
    int co = tid >> 1, k0 = (tid & 1) * 32;
    const float* wsrc = (co < 64) ? (tvw + co * 64) : (fvw + (co - 64) * 64);
#pragma unroll
    for (int g = 0; g < 4; ++g) {
      float4 f0 = *(const float4*)(wsrc + k0 + g * 8);
      float4 f1 = *(const float4*)(wsrc + k0 + g * 8 + 4);
      *(s16x8*)(Wv + co * 72 + k0 + g * 8) = pack_bf8(f0, f1);
    }
    if (tid < 128) bia[tid] = (tid < 64) ? tvb[tid] : fvb[tid - 64];
  }
  {
    int mp = (tid & 31) * 4, k0 = (tid >> 5) * 8;
    const short* spT = ZT + ((size_t)(n * 64 + k0)) * HW + p0 + mp;
    const short* spF = ZF + ((size_t)(n * 64 + k0)) * HW + p0 + mp;
    s16x8 t0, t1, t2, t3;
#pragma unroll
    for (int j = 0; j < 8; ++j) {
      s16x4 vv = *(const s16x4*)(spT + (size_t)j * HW);
      t0[j] = vv[0]; t1[j] = vv[1]; t2[j] = vv[2]; t3[j] = vv[3];
    }
    *(s16x8*)(Zts + (mp + 0) * 72 + k0) = t0;
    *(s16x8*)(Zts + (mp + 1) * 72 + k0) = t1;
    *(s16x8*)(Zts + (mp + 2) * 72 + k0) = t2;
    *(s16x8*)(Zts + (mp + 3) * 72 + k0) = t3;
#pragma unroll
    for (int j = 0; j < 8; ++j) {
      s16x4 vv = *(const s16x4*)(spF + (size_t)j * HW);
      t0[j] = vv[0]; t1[j] = vv[1]; t2[j] = vv[2]; t3[j] = vv[3];
    }
    *(s16x8*)(Zfs + (mp + 0) * 72 + k0) = t0;
    *(s16x8*)(Zfs + (mp + 1) * 72 + k0) = t1;
    *(s16x8*)(Zfs + (mp + 2) * 72 + k0) = t2;
    *(s16x8*)(Zfs + (mp + 3) * 72 + k0) = t3;
  }
  __syncthreads();
  int lane = tid & 63, wv = tid >> 6, fr = lane & 15, q = lane >> 4;
  int wm = wv * 32;
  f32x4 at_[2][4], af_[2][4];
#pragma unroll
  for (int mi = 0; mi < 2; ++mi)
#pragma unroll
    for (int ni = 0; ni < 4; ++ni) {
      at_[mi][ni] = (f32x4){0.f, 0.f, 0.f, 0.f};
      af_[mi][ni] = (f32x4){0.f, 0.f, 0.f, 0.f};
    }
#pragma unroll
  for (int ks = 0; ks < 2; ++ks) {
    bf16x8 zt_[2], zf_[2], wt_[4], wf_[4];
#pragma unroll
    for (int mi = 0; mi < 2; ++mi) {
      zt_[mi] = *(const bf16x8*)(Zts + (wm + mi * 16 + fr) * 72 + ks * 32 + q * 8);
      zf_[mi] = *(const bf16x8*)(Zfs + (wm + mi * 16 + fr) * 72 + ks * 32 + q * 8);
    }
#pragma unroll
    for (int ni = 0; ni < 4; ++ni) {
      wt_[ni] = *(const bf16x8*)(Wv + (ni * 16 + fr) * 72 + ks * 32 + q * 8);
      wf_[ni] = *(const bf16x8*)(Wv + (64 + ni * 16 + fr) * 72 + ks * 32 + q * 8);
    }
#pragma unroll
    for (int mi = 0; mi < 2; ++mi)
#pragma unroll
      for (int ni = 0; ni < 4; ++ni) {
        at_[mi][ni] = mfma16(zt_[mi], wt_[ni], at_[mi][ni]);
        af_[mi][ni] = mfma16(zf_[mi], wf_[ni], af_[mi][ni]);
      }
  }
  float gtv = tg[0], gfv = fg[0];
#pragma unroll
  for (int mi = 0; mi < 2; ++mi)
#pragma unroll
    for (int ni = 0; ni < 4; ++ni) {
      int pl = wm + mi * 16 + q * 4;
      int co = ni * 16 + fr;
      size_t idx = ((size_t)(n * 64 + co)) * HW + p0 + pl;
      float4 xv = *(const float4*)(xn + idx);
      float bt = bia[co], bff = bia[64 + co];
      float4 ov;
      ov.x = 3.f * xv.x + gtv * (at_[mi][ni][0] + bt) + gfv * (af_[mi][ni][0] + bff);
      ov.y = 3.f * xv.y + gtv * (at_[mi][ni][1] + bt) + gfv * (af_[mi][ni][1] + bff);
      ov.z = 3.f * xv.z + gtv * (at_[mi][ni][2] + bt) + gfv * (af_[mi][ni][2] + bff);
      ov.w = 3.f * xv.w + gtv * (at_[mi][ni][3] + bt) + gfv * (af_[mi][ni][3] + bff);
      *(float4*)(outn + idx) = ov;
    }
}

// ---------------------------------------------------------------------------
extern "C" void kernel_launch(void* const* d_in, const int* in_sizes, int n_in,
                              void* d_out, int out_size, void* d_ws, size_t ws_size,
                              hipStream_t stream) {
  (void)in_sizes; (void)n_in; (void)out_size;
  const float* x   = (const float*)d_in[0];
  const float* tqw = (const float*)d_in[1];
  const float* tqb = (const float*)d_in[2];
  const float* tkw = (const float*)d_in[3];
  const float* tkb = (const float*)d_in[4];
  const float* tvw = (const float*)d_in[5];
  const float* tvb = (const float*)d_in[6];
  const float* tg  = (const float*)d_in[7];
  const float* fqw = (const float*)d_in[8];
  const float* fqb = (const float*)d_in[9];
  const float* fkw = (const float*)d_in[10];
  const float* fkb = (const float*)d_in[11];
  const float* fvw = (const float*)d_in[12];
  const float* fvb = (const float*)d_in[13];
  const float* fg  = (const float*)d_in[14];
  float* out = (float*)d_out;

  // per-batch bytes: xb 32M + xt 32M + QK 16M + ZT 32M + ZF 32M + Ab 0.5M
  const size_t per_n = ((size_t)64 * HW * 2) * 2   // xb, xt
                     + ((size_t)8 * HW * 2) * 4    // QT,KT,QF,KF
                     + ((size_t)64 * HW * 2) * 2   // ZT, ZF
                     + (size_t)HW * 2;             // Ab
  int nb = (ws_size >= 4 * per_n) ? 4 : (ws_size >= 2 * per_n) ? 2 : 1;

  char* w = (char*)d_ws;
  size_t sz_x  = (size_t)nb * 64 * HW * 2;   // xb / xt each
  size_t sz_qk = (size_t)nb * 8 * HW * 2;    // each of QT/KT/QF/KF
  size_t sz_z  = (size_t)nb * 64 * HW * 2;   // each of ZT/ZF
  short* xb = (short*)(w);
  short* xt = (short*)(w + sz_x);
  short* QT = (short*)(w + 2 * sz_x);
  short* KT = (short*)(w + 2 * sz_x + sz_qk);
  short* QF = (short*)(w + 2 * sz_x + 2 * sz_qk);
  short* KF = (short*)(w + 2 * sz_x + 3 * sz_qk);
  short* ZT = (short*)(w + 2 * sz_x + 4 * sz_qk);
  short* ZF = (short*)(w + 2 * sz_x + 4 * sz_qk + sz_z);
  short* Ab = (short*)(w + 2 * sz_x + 4 * sz_qk + 2 * sz_z);
  // split-K energy partials alias the not-yet-written Z buffers:
  float* EbT = (float*)ZT;   // nb*8*HW fp32 = 8M*nb <= 32M*nb  OK
  float* EbF = (float*)ZF;

  for (int n0 = 0; n0 < 4; n0 += nb) {
    const float* xn = x + (size_t)n0 * 64 * HW;
    float* outn = out + (size_t)n0 * 64 * HW;
    cast_k<<<dim3(8, 8, nb * 64), dim3(256), 0, stream>>>(xn, xb, xt);
    conv_qk_k<<<dim3(nb * 2048), dim3(256), 0, stream>>>(
        xb, tqw, tqb, tkw, tkb, fqw, fqb, fkw, fkb, QT, KT, QF, KF);
    // energy_t: per z=(n*8+c), E_part[z] = Qt[n,c] @ Kt[n,c]^T (K=512)
    gemm_k<0, 0, false><<<dim3(4, 4, nb * 8), dim3(256), 0, stream>>>(
        QT, (long)HW, 0, 512, KT, (long)HW, 0, 512, EbT, (long)HW);
    softmax8_k<<<dim3(nb * 128), dim3(256), 0, stream>>>(EbT, Ab);
    // Zt[n,c][h][w] = sum_g At[n][h][g] * xt[n,c][w][g]
    gemm_k<0, 0, true><<<dim3(4, 4, nb * 64), dim3(256), 0, stream>>>(
        Ab, (long)HW, 6, 512, xt, (long)HW, 0, 512, ZT, (long)HW);
    // energy_f: per z=(n*8+c), E_part[z][w][v] = sum_h Qf[c][h][w]*Kf[c][h][v]
    gemm_k<2, 2, false><<<dim3(4, 4, nb * 8), dim3(256), 0, stream>>>(
        QF, (long)HW, 0, 512, KF, (long)HW, 0, 512, EbF, (long)HW);
    softmax8_k<<<dim3(nb * 128), dim3(256), 0, stream>>>(EbF, Ab);
    // Zf[n,c][h][w] = sum_v xb[n,c][h][v] * Af[n][w][v]
    gemm_k<0, 0, true><<<dim3(4, 4, nb * 64), dim3(256), 0, stream>>>(
        xb, (long)HW, 0, 512, Ab, (long)HW, 6, 512, ZF, (long)HW);
    final_k<<<dim3(nb * 2048), dim3(256), 0, stream>>>(
        ZT, ZF, xn, tvw, tvb, fvw, fvb, tg, fg, outn);
  }
}

// Round 3
// 977.058 us; speedup vs baseline: 1.3337x; 1.0491x over previous
//
#include <hip/hip_runtime.h>
#include <stdint.h>

#define HW 262144      // 512*512
#define LDIM 512

typedef __bf16 bf16x8 __attribute__((ext_vector_type(8)));
typedef float f32x4 __attribute__((ext_vector_type(4)));
typedef short s16x8 __attribute__((ext_vector_type(8)));
typedef short s16x4 __attribute__((ext_vector_type(4)));

__device__ __forceinline__ unsigned short f2bf(float f) {
  union { float f; unsigned u; } v; v.f = f;
  unsigned r = v.u + 0x7fffu + ((v.u >> 16) & 1u);
  return (unsigned short)(r >> 16);
}

__device__ __forceinline__ float bf2f(short s) {
  union { unsigned u; float f; } v;
  v.u = ((unsigned)(unsigned short)s) << 16;
  return v.f;
}

__device__ __forceinline__ s16x8 pack_bf8(float4 a, float4 b) {
  s16x8 r;
  r[0] = (short)f2bf(a.x); r[1] = (short)f2bf(a.y);
  r[2] = (short)f2bf(a.z); r[3] = (short)f2bf(a.w);
  r[4] = (short)f2bf(b.x); r[5] = (short)f2bf(b.y);
  r[6] = (short)f2bf(b.z); r[7] = (short)f2bf(b.w);
  return r;
}

__device__ __forceinline__ f32x4 mfma16(bf16x8 a, bf16x8 b, f32x4 c) {
  return __builtin_amdgcn_mfma_f32_16x16x32_bf16(a, b, c, 0, 0, 0);
}

// async global->LDS, 16B per lane, LDS dest = wave-uniform base + lane*16
__device__ __forceinline__ void gl_lds16(const short* g, short* l) {
  __builtin_amdgcn_global_load_lds(
      (const __attribute__((address_space(1))) void*)g,
      (__attribute__((address_space(3))) void*)l, 16, 0, 0);
}

// ---------------------------------------------------------------------------
// cast x (fp32) -> xb bf16 [c][h][w] and xt bf16 [c][w][h] (64x64 LDS transpose)
// grid: (8 wtile, 8 htile, nb*64)
// ---------------------------------------------------------------------------
__global__ __launch_bounds__(256) void cast_k(const float* __restrict__ x,
                                              short* __restrict__ xb,
                                              short* __restrict__ xt) {
  __shared__ short L[64][72];
  int z = blockIdx.z;
  int h0 = blockIdx.y * 64, w0 = blockIdx.x * 64;
  int tid = threadIdx.x;
  size_t base = (size_t)z * HW;
  int hl = tid >> 4;          // 0..15
  int wl = (tid & 15) * 4;    // 0..60
#pragma unroll
  for (int it = 0; it < 4; ++it) {
    int h = h0 + hl + it * 16;
    float4 v = *(const float4*)(x + base + (size_t)h * 512 + w0 + wl);
    s16x4 b;
    b[0] = (short)f2bf(v.x); b[1] = (short)f2bf(v.y);
    b[2] = (short)f2bf(v.z); b[3] = (short)f2bf(v.w);
    *(s16x4*)(xb + base + (size_t)h * 512 + w0 + wl) = b;
    L[wl + 0][hl + it * 16] = b[0];
    L[wl + 1][hl + it * 16] = b[1];
    L[wl + 2][hl + it * 16] = b[2];
    L[wl + 3][hl + it * 16] = b[3];
  }
  __syncthreads();
#pragma unroll
  for (int it = 0; it < 4; ++it) {
    int w = hl + it * 16;
    s16x4 v = *(const s16x4*)(&L[w][wl]);   // wl is h-offset here
    *(s16x4*)(xt + base + (size_t)(w0 + w) * 512 + h0 + wl) = v;
  }
}

// ---------------------------------------------------------------------------
// prep: cast tv_w / fv_w (64x64 fp32 each) to bf16 at Wvb[0..4095] / [4096..]
// ---------------------------------------------------------------------------
__global__ __launch_bounds__(256) void prep_k(const float* __restrict__ tvw,
                                              const float* __restrict__ fvw,
                                              short* __restrict__ Wvb) {
  int t = threadIdx.x;
#pragma unroll
  for (int i = 0; i < 2; ++i) {
    int idx = (i * 256 + t) * 8;
    float4 a = *(const float4*)(tvw + idx);
    float4 b = *(const float4*)(tvw + idx + 4);
    *(s16x8*)(Wvb + idx) = pack_bf8(a, b);
    a = *(const float4*)(fvw + idx);
    b = *(const float4*)(fvw + idx + 4);
    *(s16x8*)(Wvb + 4096 + idx) = pack_bf8(a, b);
  }
}

// ---------------------------------------------------------------------------
// Async GEMM (m97 structure): C[m][n] = sum_k A[m][k]*B[n][k], K=512, ld=512,
// both operands K-contiguous bf16. 128x128 tile, BK=32, unpadded [128][32]
// LDS, staged via global_load_lds dwordx4.
// ---------------------------------------------------------------------------
template<bool OBF>
__global__ __launch_bounds__(256, 4) void gemm_a(
    const short* __restrict__ A0, long az, int zshA,
    const short* __restrict__ B0, long bz, int zshB,
    void* __restrict__ C0, long cz) {
  __shared__ __align__(16) short As[128 * 32];
  __shared__ __align__(16) short Bs[128 * 32];
  int tid = threadIdx.x;
  int z = blockIdx.z;
  int m0g = blockIdx.y * 128, n0g = blockIdx.x * 128;
  const short* Abz = A0 + (size_t)(z >> zshA) * (size_t)az;
  const short* Bbz = B0 + (size_t)(z >> zshB) * (size_t)bz;
  int lane = tid & 63, wv = tid >> 6;
  int wm = (wv >> 1) * 64, wn = (wv & 1) * 64;
  int fr = lane & 15, q = lane >> 4;

  // staging map: wave wv covers rows [wv*32, wv*32+32) via 2 issues of 16 rows
  int srow = lane >> 2;         // 0..15
  int sch = (lane & 3) * 8;     // short offset within row
  const short* ga0 = Abz + (size_t)(m0g + wv * 32 + srow) * 512 + sch;
  const short* ga1 = ga0 + 16 * 512;
  const short* gb0 = Bbz + (size_t)(n0g + wv * 32 + srow) * 512 + sch;
  const short* gb1 = gb0 + 16 * 512;
  short* la0 = As + (wv * 32) * 32;
  short* la1 = As + (wv * 32 + 16) * 32;
  short* lb0 = Bs + (wv * 32) * 32;
  short* lb1 = Bs + (wv * 32 + 16) * 32;

  f32x4 acc[4][4];
#pragma unroll
  for (int mi = 0; mi < 4; ++mi)
#pragma unroll
    for (int ni = 0; ni < 4; ++ni) acc[mi][ni] = (f32x4){0.f, 0.f, 0.f, 0.f};

  for (int kk = 0; kk < 512; kk += 32) {
    gl_lds16(ga0 + kk, la0);
    gl_lds16(ga1 + kk, la1);
    gl_lds16(gb0 + kk, lb0);
    gl_lds16(gb1 + kk, lb1);
    __syncthreads();
    bf16x8 af[4], bg[4];
#pragma unroll
    for (int mi = 0; mi < 4; ++mi)
      af[mi] = *(const bf16x8*)(As + (wm + mi * 16 + fr) * 32 + q * 8);
#pragma unroll
    for (int ni = 0; ni < 4; ++ni)
      bg[ni] = *(const bf16x8*)(Bs + (wn + ni * 16 + fr) * 32 + q * 8);
#pragma unroll
    for (int mi = 0; mi < 4; ++mi)
#pragma unroll
      for (int ni = 0; ni < 4; ++ni)
        acc[mi][ni] = mfma16(af[mi], bg[ni], acc[mi][ni]);
    __syncthreads();
  }

  size_t coff = (size_t)z * (size_t)cz;
#pragma unroll
  for (int mi = 0; mi < 4; ++mi)
#pragma unroll
    for (int ni = 0; ni < 4; ++ni) {
      int row = m0g + wm + mi * 16 + q * 4;
      int col = n0g + wn + ni * 16 + fr;
#pragma unroll
      for (int r = 0; r < 4; ++r) {
        float v = acc[mi][ni][r];
        if constexpr (OBF) {
          ((short*)C0)[coff + (size_t)(row + r) * LDIM + col] = (short)f2bf(v);
        } else {
          ((float*)C0)[coff + (size_t)(row + r) * LDIM + col] = v;
        }
      }
    }
}

// ---------------------------------------------------------------------------
// energy_f GEMM: both operands M-contiguous (k-strided) bf16; padded LDS,
// register transpose staging. C fp32.
// ---------------------------------------------------------------------------
__global__ __launch_bounds__(256, 2) void gemm_t(
    const short* __restrict__ A0, long az,
    const short* __restrict__ B0, long bz,
    float* __restrict__ C0, long cz) {
  __shared__ __align__(16) short As[128 * 40];
  __shared__ __align__(16) short Bs[128 * 40];
  int tid = threadIdx.x;
  int z = blockIdx.z;
  int m0g = blockIdx.y * 128, n0g = blockIdx.x * 128;
  const short* Abz = A0 + (size_t)z * (size_t)az;
  const short* Bbz = B0 + (size_t)z * (size_t)bz;
  int lane = tid & 63, wv = tid >> 6;
  int wm = (wv >> 1) * 64, wn = (wv & 1) * 64;
  int fr = lane & 15, q = lane >> 4;
  int mp = (tid & 63) * 2, k0 = (tid >> 6) * 8;

  f32x4 acc[4][4];
#pragma unroll
  for (int mi = 0; mi < 4; ++mi)
#pragma unroll
    for (int ni = 0; ni < 4; ++ni) acc[mi][ni] = (f32x4){0.f, 0.f, 0.f, 0.f};

  for (int kk = 0; kk < 512; kk += 32) {
    {
      const short* s = Abz + (size_t)(kk + k0) * 512 + m0g + mp;
      s16x8 c0, c1;
#pragma unroll
      for (int j = 0; j < 8; ++j) {
        unsigned v = *(const unsigned*)(s + (size_t)j * 512);
        c0[j] = (short)(v & 0xffffu);
        c1[j] = (short)(v >> 16);
      }
      *(s16x8*)(As + mp * 40 + k0) = c0;
      *(s16x8*)(As + (mp + 1) * 40 + k0) = c1;
    }
    {
      const short* s = Bbz + (size_t)(kk + k0) * 512 + n0g + mp;
      s16x8 c0, c1;
#pragma unroll
      for (int j = 0; j < 8; ++j) {
        unsigned v = *(const unsigned*)(s + (size_t)j * 512);
        c0[j] = (short)(v & 0xffffu);
        c1[j] = (short)(v >> 16);
      }
      *(s16x8*)(Bs + mp * 40 + k0) = c0;
      *(s16x8*)(Bs + (mp + 1) * 40 + k0) = c1;
    }
    __syncthreads();
    bf16x8 af[4], bg[4];
#pragma unroll
    for (int mi = 0; mi < 4; ++mi)
      af[mi] = *(const bf16x8*)(As + (wm + mi * 16 + fr) * 40 + q * 8);
#pragma unroll
    for (int ni = 0; ni < 4; ++ni)
      bg[ni] = *(const bf16x8*)(Bs + (wn + ni * 16 + fr) * 40 + q * 8);
#pragma unroll
    for (int mi = 0; mi < 4; ++mi)
#pragma unroll
      for (int ni = 0; ni < 4; ++ni)
        acc[mi][ni] = mfma16(af[mi], bg[ni], acc[mi][ni]);
    __syncthreads();
  }

  size_t coff = (size_t)z * (size_t)cz;
#pragma unroll
  for (int mi = 0; mi < 4; ++mi)
#pragma unroll
    for (int ni = 0; ni < 4; ++ni) {
      int row = m0g + wm + mi * 16 + q * 4;
      int col = n0g + wn + ni * 16 + fr;
#pragma unroll
      for (int r = 0; r < 4; ++r)
        C0[coff + (size_t)(row + r) * LDIM + col] = acc[mi][ni][r];
    }
}

// ---------------------------------------------------------------------------
// Q/K conv from bf16 xb: 128 spatial positions x 32 output channels
// ---------------------------------------------------------------------------
__global__ __launch_bounds__(256, 2) void conv_qk_k(
    const short* __restrict__ xb,
    const float* __restrict__ tqw, const float* __restrict__ tqb,
    const float* __restrict__ tkw, const float* __restrict__ tkb,
    const float* __restrict__ fqw, const float* __restrict__ fqb,
    const float* __restrict__ fkw, const float* __restrict__ fkb,
    short* __restrict__ QT, short* __restrict__ KT,
    short* __restrict__ QF, short* __restrict__ KF) {
  __shared__ __align__(16) short As[128 * 72];   // x^T tile [p][ci]
  __shared__ __align__(16) short Ws[32 * 72];    // weights [co][ci]
  __shared__ float bia[32];
  int tid = threadIdx.x;
  int n = blockIdx.x >> 11;
  int p0 = (blockIdx.x & 2047) << 7;
  {
    int co = tid >> 3, k0 = (tid & 7) * 8;
    const float* wsrc = (co < 8) ? tqw : (co < 16) ? tkw : (co < 24) ? fqw : fkw;
    const float* sp = wsrc + (co & 7) * 64 + k0;
    float4 f0 = *(const float4*)sp;
    float4 f1 = *(const float4*)(sp + 4);
    *(s16x8*)(Ws + co * 72 + k0) = pack_bf8(f0, f1);
    if (tid < 32) {
      const float* bsrc = (tid < 8) ? tqb : (tid < 16) ? tkb : (tid < 24) ? fqb : fkb;
      bia[tid] = bsrc[tid & 7];
    }
  }
  {
    int mp = (tid & 31) * 4, k0 = (tid >> 5) * 8;
    const short* sp = xb + ((size_t)(n * 64 + k0)) * HW + p0 + mp;
    s16x8 t0, t1, t2, t3;
#pragma unroll
    for (int j = 0; j < 8; ++j) {
      s16x4 vv = *(const s16x4*)(sp + (size_t)j * HW);
      t0[j] = vv[0]; t1[j] = vv[1]; t2[j] = vv[2]; t3[j] = vv[3];
    }
    *(s16x8*)(As + (mp + 0) * 72 + k0) = t0;
    *(s16x8*)(As + (mp + 1) * 72 + k0) = t1;
    *(s16x8*)(As + (mp + 2) * 72 + k0) = t2;
    *(s16x8*)(As + (mp + 3) * 72 + k0) = t3;
  }
  __syncthreads();
  int lane = tid & 63, wv = tid >> 6, fr = lane & 15, q = lane >> 4;
  int wm = wv * 32;
  f32x4 acc[2][2];
#pragma unroll
  for (int mi = 0; mi < 2; ++mi)
#pragma unroll
    for (int ni = 0; ni < 2; ++ni) acc[mi][ni] = (f32x4){0.f, 0.f, 0.f, 0.f};
#pragma unroll
  for (int ks = 0; ks < 2; ++ks) {
    bf16x8 af[2], bf_[2];
#pragma unroll
    for (int mi = 0; mi < 2; ++mi)
      af[mi] = *(const bf16x8*)(As + (wm + mi * 16 + fr) * 72 + ks * 32 + q * 8);
#pragma unroll
    for (int ni = 0; ni < 2; ++ni)
      bf_[ni] = *(const bf16x8*)(Ws + (ni * 16 + fr) * 72 + ks * 32 + q * 8);
#pragma unroll
    for (int mi = 0; mi < 2; ++mi)
#pragma unroll
      for (int ni = 0; ni < 2; ++ni)
        acc[mi][ni] = mfma16(af[mi], bf_[ni], acc[mi][ni]);
  }
#pragma unroll
  for (int mi = 0; mi < 2; ++mi)
#pragma unroll
    for (int ni = 0; ni < 2; ++ni) {
      int pl = wm + mi * 16 + q * 4;
      int co = ni * 16 + fr;
      float b = bia[co];
      short* dstt = (co < 8) ? QT : (co < 16) ? KT : (co < 24) ? QF : KF;
      short* d = dstt + ((size_t)(n * 8 + (co & 7))) * HW + p0 + pl;
      s16x4 sv;
#pragma unroll
      for (int r = 0; r < 4; ++r) sv[r] = (short)f2bf(acc[mi][ni][r] + b);
      *(s16x4*)d = sv;
    }
}

// ---------------------------------------------------------------------------
// Row softmax over 512 logits with 8-way split-K partial sum.
// ---------------------------------------------------------------------------
__global__ __launch_bounds__(256, 4) void softmax8_k(const float* __restrict__ Ep,
                                                     short* __restrict__ A) {
  int tid = threadIdx.x;
  int lane = tid & 63, wv = tid >> 6;
  int row = blockIdx.x * 4 + wv;        // n*512 + h
  int n = row >> 9, h = row & 511;
  const float* base = Ep + (size_t)(n * 8) * HW + (size_t)h * 512 + lane * 8;
  float v[8] = {0.f, 0.f, 0.f, 0.f, 0.f, 0.f, 0.f, 0.f};
#pragma unroll
  for (int cc = 0; cc < 8; ++cc) {
    const float* e = base + (size_t)cc * HW;
    float4 a = *(const float4*)e;
    float4 b = *(const float4*)(e + 4);
    v[0] += a.x; v[1] += a.y; v[2] += a.z; v[3] += a.w;
    v[4] += b.x; v[5] += b.y; v[6] += b.z; v[7] += b.w;
  }
  float m = v[0];
#pragma unroll
  for (int j = 1; j < 8; ++j) m = fmaxf(m, v[j]);
#pragma unroll
  for (int off = 32; off >= 1; off >>= 1) m = fmaxf(m, __shfl_xor(m, off));
  float s = 0.f;
#pragma unroll
  for (int j = 0; j < 8; ++j) {
    v[j] = __expf(v[j] - m);
    s += v[j];
  }
#pragma unroll
  for (int off = 32; off >= 1; off >>= 1) s += __shfl_xor(s, off);
  float inv = 1.f / s;
  s16x8 o;
#pragma unroll
  for (int j = 0; j < 8; ++j) o[j] = (short)f2bf(v[j] * inv);
  *(s16x8*)(A + (size_t)row * LDIM + lane * 8) = o;
}

// ---------------------------------------------------------------------------
// Final: out = 3x + gt*(Wt@Zt + bt) + gf*(Wf@Zf + bf), per 128-position tile.
// Weights from global bf16 (Wvb), x from bf16 (xb). LDS only for Z transpose.
// ---------------------------------------------------------------------------
__global__ __launch_bounds__(256, 3) void final_k(
    const short* __restrict__ ZT, const short* __restrict__ ZF,
    const short* __restrict__ xb, const short* __restrict__ Wvb,
    const float* __restrict__ tvb, const float* __restrict__ fvb,
    const float* __restrict__ tg, const float* __restrict__ fg,
    float* __restrict__ outn) {
  __shared__ __align__(16) short Zts[128 * 72];
  __shared__ __align__(16) short Zfs[128 * 72];
  __shared__ float bia[128];
  int tid = threadIdx.x;
  int n = blockIdx.x >> 11;
  int p0 = (blockIdx.x & 2047) << 7;
  if (tid < 128) bia[tid] = (tid < 64) ? tvb[tid] : fvb[tid - 64];
  {
    int mp = (tid & 31) * 4, k0 = (tid >> 5) * 8;
    const short* spT = ZT + ((size_t)(n * 64 + k0)) * HW + p0 + mp;
    const short* spF = ZF + ((size_t)(n * 64 + k0)) * HW + p0 + mp;
    s16x8 t0, t1, t2, t3;
#pragma unroll
    for (int j = 0; j < 8; ++j) {
      s16x4 vv = *(const s16x4*)(spT + (size_t)j * HW);
      t0[j] = vv[0]; t1[j] = vv[1]; t2[j] = vv[2]; t3[j] = vv[3];
    }
    *(s16x8*)(Zts + (mp + 0) * 72 + k0) = t0;
    *(s16x8*)(Zts + (mp + 1) * 72 + k0) = t1;
    *(s16x8*)(Zts + (mp + 2) * 72 + k0) = t2;
    *(s16x8*)(Zts + (mp + 3) * 72 + k0) = t3;
#pragma unroll
    for (int j = 0; j < 8; ++j) {
      s16x4 vv = *(const s16x4*)(spF + (size_t)j * HW);
      t0[j] = vv[0]; t1[j] = vv[1]; t2[j] = vv[2]; t3[j] = vv[3];
    }
    *(s16x8*)(Zfs + (mp + 0) * 72 + k0) = t0;
    *(s16x8*)(Zfs + (mp + 1) * 72 + k0) = t1;
    *(s16x8*)(Zfs + (mp + 2) * 72 + k0) = t2;
    *(s16x8*)(Zfs + (mp + 3) * 72 + k0) = t3;
  }
  __syncthreads();
  int lane = tid & 63, wv = tid >> 6, fr = lane & 15, q = lane >> 4;
  int wm = wv * 32;
  f32x4 at_[2][4], af_[2][4];
#pragma unroll
  for (int mi = 0; mi < 2; ++mi)
#pragma unroll
    for (int ni = 0; ni < 4; ++ni) {
      at_[mi][ni] = (f32x4){0.f, 0.f, 0.f, 0.f};
      af_[mi][ni] = (f32x4){0.f, 0.f, 0.f, 0.f};
    }
#pragma unroll
  for (int ks = 0; ks < 2; ++ks) {
    bf16x8 zt_[2], zf_[2], wt_[4], wf_[4];
#pragma unroll
    for (int mi = 0; mi < 2; ++mi) {
      zt_[mi] = *(const bf16x8*)(Zts + (wm + mi * 16 + fr) * 72 + ks * 32 + q * 8);
      zf_[mi] = *(const bf16x8*)(Zfs + (wm + mi * 16 + fr) * 72 + ks * 32 + q * 8);
    }
#pragma unroll
    for (int ni = 0; ni < 4; ++ni) {
      wt_[ni] = *(const bf16x8*)(Wvb + (ni * 16 + fr) * 64 + ks * 32 + q * 8);
      wf_[ni] = *(const bf16x8*)(Wvb + 4096 + (ni * 16 + fr) * 64 + ks * 32 + q * 8);
    }
#pragma unroll
    for (int mi = 0; mi < 2; ++mi)
#pragma unroll
      for (int ni = 0; ni < 4; ++ni) {
        at_[mi][ni] = mfma16(zt_[mi], wt_[ni], at_[mi][ni]);
        af_[mi][ni] = mfma16(zf_[mi], wf_[ni], af_[mi][ni]);
      }
  }
  float gtv = tg[0], gfv = fg[0];
#pragma unroll
  for (int mi = 0; mi < 2; ++mi)
#pragma unroll
    for (int ni = 0; ni < 4; ++ni) {
      int pl = wm + mi * 16 + q * 4;
      int co = ni * 16 + fr;
      size_t idx = ((size_t)(n * 64 + co)) * HW + p0 + pl;
      s16x4 xv = *(const s16x4*)(xb + idx);
      float bt = bia[co], bff = bia[64 + co];
      float4 ov;
      ov.x = 3.f * bf2f(xv[0]) + gtv * (at_[mi][ni][0] + bt) + gfv * (af_[mi][ni][0] + bff);
      ov.y = 3.f * bf2f(xv[1]) + gtv * (at_[mi][ni][1] + bt) + gfv * (af_[mi][ni][1] + bff);
      ov.z = 3.f * bf2f(xv[2]) + gtv * (at_[mi][ni][2] + bt) + gfv * (af_[mi][ni][2] + bff);
      ov.w = 3.f * bf2f(xv[3]) + gtv * (at_[mi][ni][3] + bt) + gfv * (af_[mi][ni][3] + bff);
      *(float4*)(outn + idx) = ov;
    }
}

// ---------------------------------------------------------------------------
extern "C" void kernel_launch(void* const* d_in, const int* in_sizes, int n_in,
                              void* d_out, int out_size, void* d_ws, size_t ws_size,
                              hipStream_t stream) {
  (void)in_sizes; (void)n_in; (void)out_size;
  const float* x   = (const float*)d_in[0];
  const float* tqw = (const float*)d_in[1];
  const float* tqb = (const float*)d_in[2];
  const float* tkw = (const float*)d_in[3];
  const float* tkb = (const float*)d_in[4];
  const float* tvw = (const float*)d_in[5];
  const float* tvb = (const float*)d_in[6];
  const float* tg  = (const float*)d_in[7];
  const float* fqw = (const float*)d_in[8];
  const float* fqb = (const float*)d_in[9];
  const float* fkw = (const float*)d_in[10];
  const float* fkb = (const float*)d_in[11];
  const float* fvw = (const float*)d_in[12];
  const float* fvb = (const float*)d_in[13];
  const float* fg  = (const float*)d_in[14];
  float* out = (float*)d_out;

  // per-batch: xb 32M + (xt==ZF) 32M + QK 16M + ZT 32M + Ab 0.5M  (+16K Wvb)
  const size_t per_n = ((size_t)64 * HW * 2) * 3    // xb, xt/ZF, ZT
                     + ((size_t)8 * HW * 2) * 4     // QT,KT,QF,KF
                     + (size_t)HW * 2;              // Ab
  int nb = (ws_size >= 4 * per_n + 16384) ? 4
         : (ws_size >= 2 * per_n + 16384) ? 2 : 1;

  char* w = (char*)d_ws;
  short* Wvb = (short*)w;                    // 16 KB
  char* wb = w + 16384;
  size_t sz_x  = (size_t)nb * 64 * HW * 2;   // xb / xt / ZT / ZF each
  size_t sz_qk = (size_t)nb * 8 * HW * 2;    // each of QT/KT/QF/KF
  short* xb = (short*)(wb);
  short* ZF = (short*)(wb + sz_x);           // aliases xt (xt dead before ZF use)
  short* xt = ZF;
  short* QT = (short*)(wb + 2 * sz_x);
  short* KT = (short*)(wb + 2 * sz_x + sz_qk);
  short* QF = (short*)(wb + 2 * sz_x + 2 * sz_qk);
  short* KF = (short*)(wb + 2 * sz_x + 3 * sz_qk);
  short* ZT = (short*)(wb + 2 * sz_x + 4 * sz_qk);
  short* Ab = (short*)(wb + 3 * sz_x + 4 * sz_qk);
  float* EbT = (float*)ZT;   // energy_t partials (dead before Zt written)
  float* EbF = (float*)ZF;   // energy_f partials (xt dead by then; dead before Zf)

  prep_k<<<dim3(1), dim3(256), 0, stream>>>(tvw, fvw, Wvb);

  for (int n0 = 0; n0 < 4; n0 += nb) {
    const float* xn = x + (size_t)n0 * 64 * HW;
    float* outn = out + (size_t)n0 * 64 * HW;
    cast_k<<<dim3(8, 8, nb * 64), dim3(256), 0, stream>>>(xn, xb, xt);
    conv_qk_k<<<dim3(nb * 2048), dim3(256), 0, stream>>>(
        xb, tqw, tqb, tkw, tkb, fqw, fqb, fkw, fkb, QT, KT, QF, KF);
    // energy_t partials: per z=(n*8+c), Qt[z] @ Kt[z]^T (K=512)
    gemm_a<false><<<dim3(4, 4, nb * 8), dim3(256), 0, stream>>>(
        QT, (long)HW, 0, KT, (long)HW, 0, EbT, (long)HW);
    softmax8_k<<<dim3(nb * 128), dim3(256), 0, stream>>>(EbT, Ab);
    // Zt[n,c][h][w] = sum_g At[n][h][g] * xt[n,c][w][g]
    gemm_a<true><<<dim3(4, 4, nb * 64), dim3(256), 0, stream>>>(
        Ab, (long)HW, 6, xt, (long)HW, 0, ZT, (long)HW);
    // energy_f partials: per z, E[w][v] = sum_h Qf[z][h][w]*Kf[z][h][v]
    gemm_t<<<dim3(4, 4, nb * 8), dim3(256), 0, stream>>>(
        QF, (long)HW, KF, (long)HW, EbF, (long)HW);
    softmax8_k<<<dim3(nb * 128), dim3(256), 0, stream>>>(EbF, Ab);
    // Zf[n,c][h][w] = sum_v xb[n,c][h][v] * Af[n][w][v]
    gemm_a<true><<<dim3(4, 4, nb * 64), dim3(256), 0, stream>>>(
        xb, (long)HW, 0, Ab, (long)HW, 6, ZF, (long)HW);
    final_k<<<dim3(nb * 2048), dim3(256), 0, stream>>>(
        ZT, ZF, xb, Wvb, tvb, fvb, tg, fg, outn);
  }
}